// Round 1
// baseline (115.872 us; speedup 1.0000x reference)
//
#include <hip/hip_runtime.h>
#include <math.h>

// Problem constants (fixed by the reference harness)
#define HD      768          // hidden dim H
#define TLEN    512          // seq_len T
#define NCH     8            // NC chunks
#define NNOTE   4            // NN notes
#define ROWK    1115         // full rows of reshaped-weights per chunk (8921/8 rounded: 8*1115+? -> boundary rows handled via R[])
#define F4      192          // HD/4 float4 per row

// Balanced 256-block partition (all blocks 154-160 KB, was 197/143 split):
//   enc: 80 blocks = 8 chunks x 10 segs; segs 0..7 -> 51 rows, segs 8..9 -> 52 rows (8*51+2*52 = 512)
//   lw : 176 blocks = 8 k x 22 segs;     segs 0..14 -> 51 rows, segs 15..21 -> 50 rows (15*51+7*50 = 1115)
#define ENC_BLOCKS  80
#define LW_BLOCKS   176
#define NPART       256

// ws layout (float offsets): P[256][768] | W2[16][768] | counters (2 x u32)
#define WS2_OFF     (NPART * HD)          // 196608
#define CNT_OFF     (WS2_OFF + 16 * HD)   // 208896  (byte offset 835584)
#define FIN0        240                    // blocks 240..255: phase-2a (last indices -> deadlock-safe)
#define FIN1        252                    // blocks 252..255: phase-2b

// ---------------------------------------------------------------------------
// Single fused kernel. 256 blocks x 192 threads; thread t owns float4 column t.
// Phase 1  (all 256 blocks): byte-balanced partial column sums of enc/lw -> P.
// Phase 2a (blocks 240..255): collapse P -> B[c] (8 rows) and Tk[k] (8 rows).
// Phase 2b (blocks 252..255): scalar epilogue per h, sigmoid -> out.
// Sync: device-scope atomic counters (zeroed by an 8-byte memset on the stream).
// Spinners are the HIGHEST block indices: they only ever wait on blocks
// dispatched at-or-before themselves, so no co-residency assumption is needed
// beyond ~16 blocks (48 waves), trivially satisfied.
// ---------------------------------------------------------------------------
__global__ __launch_bounds__(192) void talc_fused_kernel(
    const float* __restrict__ enc,
    const float* __restrict__ lw,
    const int* __restrict__ ids,
    float* __restrict__ ws,
    float* __restrict__ out) {
  const int t = threadIdx.x;          // 0..191
  const int b = blockIdx.x;           // 0..255
  float4* P  = (float4*)ws;
  float4* W2 = (float4*)(ws + WS2_OFF);
  unsigned* cnt = (unsigned*)(ws + CNT_OFF);

  // ---------------- phase 1: balanced partial sums (40 MB HBM) ----------------
  {
    const float4* base;
    int rn;
    if (b < ENC_BLOCKS) {
      const int c = b / 10, seg = b - c * 10;
      const int start = (seg < 8) ? 51 * seg : 408 + 52 * (seg - 8);
      rn = (seg < 8) ? 51 : 52;
      base = (const float4*)enc + (size_t)(c * TLEN + start) * F4 + t;
    } else {
      const int l = b - ENC_BLOCKS;
      const int k = l / 22, seg = l - k * 22;
      const int start = (seg < 15) ? 51 * seg : 765 + 50 * (seg - 15);
      rn = (seg < 15) ? 51 : 50;
      base = (const float4*)lw + (size_t)(k * ROWK + start) * F4 + t;
    }
    float4 acc = make_float4(0.f, 0.f, 0.f, 0.f);
#pragma unroll 8
    for (int r = 0; r < rn; ++r) {
      float4 v = base[(size_t)r * F4];
      acc.x += v.x; acc.y += v.y; acc.z += v.z; acc.w += v.w;
    }
    P[(size_t)b * F4 + t] = acc;
  }
  __syncthreads();                       // all stores of this block issued+done
  if (t == 0) {
    __threadfence();                     // release: P row visible device-wide
    atomicAdd(&cnt[0], 1u);
  }
  if (b < FIN0) return;

  // ---------------- phase 2a: P (256 rows) -> B[c], Tk[k] (16 rows) ----------
  if (t == 0) {
    while (__hip_atomic_load(&cnt[0], __ATOMIC_RELAXED, __HIP_MEMORY_SCOPE_AGENT) < NPART)
      __builtin_amdgcn_s_sleep(8);
  }
  __syncthreads();
  __builtin_amdgcn_fence(__ATOMIC_ACQUIRE, "agent");   // invalidate stale cache
  {
    const int f = b - FIN0;              // 0..15
    float4 s = make_float4(0.f, 0.f, 0.f, 0.f);
    if (f < 8) {                         // B[c]: sum 10 enc partials of chunk f
#pragma unroll
      for (int g = 0; g < 10; ++g) {
        float4 v = P[(size_t)(f * 10 + g) * F4 + t];
        s.x += v.x; s.y += v.y; s.z += v.z; s.w += v.w;
      }
    } else {                             // Tk[k]: sum 22 lw partials of k = f-8
#pragma unroll
      for (int g = 0; g < 22; ++g) {
        float4 v = P[(size_t)(ENC_BLOCKS + (f - 8) * 22 + g) * F4 + t];
        s.x += v.x; s.y += v.y; s.z += v.z; s.w += v.w;
      }
    }
    W2[(size_t)f * F4 + t] = s;
  }
  __syncthreads();
  if (t == 0) {
    __threadfence();
    atomicAdd(&cnt[1], 1u);
  }
  if (b < FIN1) return;

  // ---------------- phase 2b: scalar epilogue, one thread per h --------------
  if (t == 0) {
    while (__hip_atomic_load(&cnt[1], __ATOMIC_RELAXED, __HIP_MEMORY_SCOPE_AGENT) < 16u)
      __builtin_amdgcn_s_sleep(8);
  }
  __syncthreads();
  __builtin_amdgcn_fence(__ATOMIC_ACQUIRE, "agent");
  {
    const int h = (b - FIN1) * 192 + t;  // 0..767
    const float* ws2 = ws + WS2_OFF;

    float B[NCH], Tk[NCH];
#pragma unroll
    for (int c = 0; c < NCH; ++c) B[c] = ws2[(size_t)c * HD + h];
#pragma unroll
    for (int k = 0; k < NCH; ++k) Tk[k] = ws2[(size_t)(8 + k) * HD + h];

    float Esuf[NCH + 1];
    Esuf[NCH] = 0.f;
#pragma unroll
    for (int c = NCH - 1; c >= 0; --c) Esuf[c] = Esuf[c + 1] + B[c];
    float Epre[NCH + 1];
    Epre[0] = 0.f;
#pragma unroll
    for (int c = 1; c <= NCH; ++c) Epre[c] = Epre[c - 1] + B[c - 1];
    const float E = Esuf[0];

    // single boundary rows R[m] = lwR[1115*m, h]
    float R[NCH + 1];
#pragma unroll
    for (int m = 0; m <= NCH; ++m) R[m] = lw[(size_t)(m * ROWK) * HD + h];

    float G[NCH];
#pragma unroll
    for (int k = 0; k < NCH; ++k)
      G[k] = R[k] * Esuf[k] + (Tk[k] - R[k]) * E + R[k + 1] * Epre[k + 1];

    int id[NNOTE];
#pragma unroll
    for (int n = 0; n < NNOTE; ++n) id[n] = ids[n];

    float score[NNOTE] = {0.f, 0.f, 0.f, 0.f};
#pragma unroll
    for (int c = 0; c < NCH; ++c) {
      int cm = 0;
#pragma unroll
      for (int n = 0; n < NNOTE; ++n) cm += (id[n] + 1 <= c) ? 1 : 0;
      const float inv = (cm > 0) ? (1.f / (float)cm) : 0.f;
#pragma unroll
      for (int n = 0; n < NNOTE; ++n) {
        const float m = (cm == 0) ? 0.25f : (((id[n] + 1) <= c) ? inv : 0.f);
        score[n] += m * G[c];
      }
    }
#pragma unroll
    for (int n = 0; n < NNOTE; ++n)
      out[(size_t)n * HD + h] = 1.f / (1.f + expf(-score[n]));
  }
}

extern "C" void kernel_launch(void* const* d_in, const int* in_sizes, int n_in,
                              void* d_out, int out_size, void* d_ws, size_t ws_size,
                              hipStream_t stream) {
  (void)in_sizes; (void)n_in; (void)out_size; (void)ws_size;
  const float* enc = (const float*)d_in[0];       // (4096, 768)
  // d_in[1] = label_queries — provably unused (softmax over notes is
  // shift-invariant; the identical-across-notes score term cancels exactly).
  const float* lw  = (const float*)d_in[2];       // (768, 8921) buffer, read as (8921, 768)
  const int*   ids = (const int*)d_in[3];         // (4,) note_end_chunk_ids (int32 after JAX x64-demotion)
  float* ws  = (float*)d_ws;
  float* out = (float*)d_out;                     // (4, 768) fp32

  // zero the two sync counters in poisoned workspace (graph-capturable stream op)
  hipMemsetAsync((char*)d_ws + (size_t)CNT_OFF * 4, 0, 8, stream);
  talc_fused_kernel<<<NPART, 192, 0, stream>>>(enc, lw, ids, ws, out);
}

// Round 2
// 104.487 us; speedup vs baseline: 1.1090x; 1.1090x over previous
//
#include <hip/hip_runtime.h>
#include <math.h>

// Problem constants (fixed by the reference harness)
#define HD      768          // hidden dim H
#define TLEN    512          // seq_len T
#define NCH     8            // NC chunks
#define NNOTE   4            // NN notes
#define ROWK    1115         // full rows of reshaped-weights per chunk
#define F4      192          // HD/4 float4 per row

// Byte-balanced 256-block partition (all blocks 154-160 KB; round-0 was 197/143):
//   enc: 80 blocks = 8 chunks x 10 segs; segs 0..7 -> 51 rows, segs 8..9 -> 52 rows (8*51+2*52 = 512)
//   lw : 176 blocks = 8 k x 22 segs;     segs 0..14 -> 51 rows, segs 15..21 -> 50 rows (15*51+7*50 = 1115)
#define ENC_BLOCKS  80
#define ENC_SEGS    10
#define LW_SEGS     22
#define LW_BLOCKS   176
#define NPART       256

// ---------------------------------------------------------------------------
// Kernel A: all the heavy memory traffic (40 MB), byte-balanced.
// 192 threads = 3 waves; thread t owns float4 column t (192*4 = 768 = H).
// One block per CU. Plain stores to ws; the kernel boundary is the (single,
// command-processor-side) release — measured cheaper than 256 in-kernel
// device-scope fences (round-1 regression: fused+fences cost +11.5 us).
// ---------------------------------------------------------------------------
__global__ __launch_bounds__(192) void talc_reduce_kernel(
    const float* __restrict__ enc,
    const float* __restrict__ lw,
    float* __restrict__ ws) {
  const int t = threadIdx.x;          // 0..191
  const int b = blockIdx.x;           // 0..255
  float4* P = (float4*)ws;            // P[256][192] float4

  const float4* base;
  int rn;
  if (b < ENC_BLOCKS) {
    const int c = b / ENC_SEGS, seg = b - c * ENC_SEGS;
    const int start = (seg < 8) ? 51 * seg : 408 + 52 * (seg - 8);
    rn = (seg < 8) ? 51 : 52;
    base = (const float4*)enc + (size_t)(c * TLEN + start) * F4 + t;
  } else {
    const int l = b - ENC_BLOCKS;
    const int k = l / LW_SEGS, seg = l - k * LW_SEGS;
    const int start = (seg < 15) ? 51 * seg : 765 + 50 * (seg - 15);
    rn = (seg < 15) ? 51 : 50;
    base = (const float4*)lw + (size_t)(k * ROWK + start) * F4 + t;
  }

  float4 acc = make_float4(0.f, 0.f, 0.f, 0.f);
#pragma unroll 8
  for (int r = 0; r < rn; ++r) {
    float4 v = base[(size_t)r * F4];
    acc.x += v.x; acc.y += v.y; acc.z += v.z; acc.w += v.w;
  }
  P[(size_t)b * F4 + t] = acc;
}

// ---------------------------------------------------------------------------
// Kernel B: finish. 6 blocks x 128 threads, one thread per h.
//   B[c]     = sum of 10 enc partials      (512-block column sums of encoding)
//   Tk[k]    = sum of 22 lw partials       (1115-row sums of reshaped weights)
//   R[m]     = lwR[1115*m, h], m=0..8      (boundary rows)
//   G[k]     = R[k]*Esuf[k] + (Tk[k]-R[k])*E + R[k+1]*Epre[k+1]
//   Mc[n][c] = softmax over notes of the chunk mask (0.25 if all masked,
//              else 1/cnt for unmasked, 0 for masked)
//   out[n,h] = sigmoid( sum_c Mc[n][c] * G[c] )
// ---------------------------------------------------------------------------
__global__ __launch_bounds__(128) void talc_finish_kernel(
    const float* __restrict__ lw,
    const int* __restrict__ ids,
    const float* __restrict__ ws,
    float* __restrict__ out) {
  const int h = blockIdx.x * 128 + threadIdx.x;   // 0..767
  if (h >= HD) return;
  const float* P = ws;

  // encoding 512-block column sums
  float B[NCH];
#pragma unroll
  for (int c = 0; c < NCH; ++c) {
    float s = 0.f;
#pragma unroll
    for (int g = 0; g < ENC_SEGS; ++g) s += P[(size_t)(c * ENC_SEGS + g) * HD + h];
    B[c] = s;
  }
  float Esuf[NCH + 1];
  Esuf[NCH] = 0.f;
#pragma unroll
  for (int c = NCH - 1; c >= 0; --c) Esuf[c] = Esuf[c + 1] + B[c];
  float Epre[NCH + 1];
  Epre[0] = 0.f;
#pragma unroll
  for (int c = 1; c <= NCH; ++c) Epre[c] = Epre[c - 1] + B[c - 1];
  const float E = Esuf[0];

  // label_weights 1115-row range sums
  float Tk[NCH];
#pragma unroll
  for (int k = 0; k < NCH; ++k) {
    float s = 0.f;
#pragma unroll
    for (int g = 0; g < LW_SEGS; ++g)
      s += P[(size_t)(ENC_BLOCKS + k * LW_SEGS + g) * HD + h];
    Tk[k] = s;
  }

  // single boundary rows R[m] = lwR[1115*m, h]
  float R[NCH + 1];
#pragma unroll
  for (int m = 0; m <= NCH; ++m) R[m] = lw[(size_t)(m * ROWK) * HD + h];

  // G[k]: top partial row + full rows + bottom partial row of chunk k's
  // region in the raw (Nn, Nl, NcT) reshape of the softmax weights.
  float G[NCH];
#pragma unroll
  for (int k = 0; k < NCH; ++k) {
    G[k] = R[k] * Esuf[k] + (Tk[k] - R[k]) * E + R[k + 1] * Epre[k + 1];
  }

  // mask softmax table Mc[n][c] and final scores
  int id[NNOTE];
#pragma unroll
  for (int n = 0; n < NNOTE; ++n) id[n] = ids[n];

  float score[NNOTE] = {0.f, 0.f, 0.f, 0.f};
#pragma unroll
  for (int c = 0; c < NCH; ++c) {
    int cnt = 0;
#pragma unroll
    for (int n = 0; n < NNOTE; ++n) cnt += (id[n] + 1 <= c) ? 1 : 0;
    const float inv = (cnt > 0) ? (1.f / (float)cnt) : 0.f;
#pragma unroll
    for (int n = 0; n < NNOTE; ++n) {
      const float m = (cnt == 0) ? 0.25f : (((id[n] + 1) <= c) ? inv : 0.f);
      score[n] += m * G[c];
    }
  }
#pragma unroll
  for (int n = 0; n < NNOTE; ++n) {
    out[(size_t)n * HD + h] = 1.f / (1.f + expf(-score[n]));
  }
}

extern "C" void kernel_launch(void* const* d_in, const int* in_sizes, int n_in,
                              void* d_out, int out_size, void* d_ws, size_t ws_size,
                              hipStream_t stream) {
  (void)in_sizes; (void)n_in; (void)out_size; (void)ws_size;
  const float* enc = (const float*)d_in[0];       // (4096, 768)
  // d_in[1] = label_queries — provably unused (softmax over notes is
  // shift-invariant; the identical-across-notes score term cancels exactly).
  const float* lw  = (const float*)d_in[2];       // (768, 8921) buffer, read as (8921, 768)
  const int*   ids = (const int*)d_in[3];         // (4,) note_end_chunk_ids
  float* ws  = (float*)d_ws;                      // 256*768 floats = 786 KB used
  float* out = (float*)d_out;                     // (4, 768) fp32

  talc_reduce_kernel<<<NPART, 192, 0, stream>>>(enc, lw, ws);
  talc_finish_kernel<<<6, 128, 0, stream>>>(lw, ids, ws, out);
}